// Round 2
// baseline (208.308 us; speedup 1.0000x reference)
//
#include <hip/hip_runtime.h>
#include <math.h>

#define B 4
#define CIN 64
#define H 128
#define W 128
#define COUT 128
#define KK 9
#define HW (H*W)

#define OFFS_SZ (B*18*HW)
#define MASK_SZ (B*9*HW)
#define WTAP2_SZ (CIN*32*12)
#define WBF_COLS 640                 // 4 chunks x 160 (144 real + 16 zero)
#define WBF_SHORTS (COUT*WBF_COLS)
#define XT_SZ (B*HW*CIN)
#define LDK 168                      // LDS k-stride (shorts); 336B row stride

typedef __attribute__((ext_vector_type(8))) short short8;
typedef __attribute__((ext_vector_type(4))) float f32x4;
typedef __attribute__((ext_vector_type(2))) float f32x2;
typedef f32x2 __attribute__((aligned(4))) f32x2a;   // align-4 float2 load

// batched gather load: volatile asm guarantees the load is issued (not
// serialized into a load->wait->use chain by the scheduler).
#define GL16(dst, ptr, OFF) \
    asm volatile("global_load_dwordx4 %0, %1, off offset:" #OFF \
                 : "=v"(dst) : "v"(ptr))

__device__ __forceinline__ unsigned short f2bf(float f) {
    unsigned int u = __float_as_uint(f);
    u += 0x7fffu + ((u >> 16) & 1u);
    return (unsigned short)(u >> 16);
}

// ---------------------------------------------------------------------------
// prep: wtap2[c][f][12] (offmask weights, t-contiguous for b128 LDS reads),
// bcat biases.
// ---------------------------------------------------------------------------
__global__ void prep_kernel(const float* __restrict__ w_off, const float* __restrict__ b_off,
                            const float* __restrict__ w_mask, const float* __restrict__ b_mask,
                            float* __restrict__ wtap2, float* __restrict__ bcat)
{
    int idx = blockIdx.x * 256 + threadIdx.x;
    if (idx < WTAP2_SZ) {
        int t = idx % 12;
        int f = (idx / 12) & 31;
        int c = idx / 384;
        float v = 0.f;
        if (t < 9) {
            if (f < 18)      v = w_off[(f * CIN + c) * 9 + t];
            else if (f < 27) v = w_mask[((f - 18) * CIN + c) * 9 + t];
        }
        wtap2[idx] = v;
    }
    if (blockIdx.x == 0 && threadIdx.x < 32) {
        int f = threadIdx.x;
        float bv = 0.f;
        if (f < 18) bv = b_off[f];
        else if (f < 27) bv = b_mask[f - 18];
        bcat[f] = bv;
    }
}

// ---------------------------------------------------------------------------
// prep_wbf: einsum weights -> bf16, layout [o][cb*160 + tap*16 + ci];
// pad cols [144,160) per chunk are ZERO.
// ---------------------------------------------------------------------------
__global__ void prep_wbf(const float* __restrict__ wgt, short* __restrict__ wbf)
{
    int idx = blockIdx.x * 256 + threadIdx.x;
    if (idx >= WBF_SHORTS) return;
    int o  = idx / WBF_COLS;
    int kp = idx % WBF_COLS;
    int cb = kp / 160, r = kp % 160;
    float v = 0.f;
    if (r < 144) {
        int tap = r >> 4;
        int c   = cb * 16 + (r & 15);
        v = wgt[(o * CIN + c) * KK + tap];
    }
    wbf[idx] = (short)f2bf(v);
}

// ---------------------------------------------------------------------------
// xpose: x NCHW f32 -> xT NHWC f32 (xT[b][y][xp][c], c fastest).
// Block = one (b,y) row: 128 px x 64 ch staged through padded LDS.
// ---------------------------------------------------------------------------
__global__ __launch_bounds__(256) void xpose_kernel(const float* __restrict__ x,
                                                    float* __restrict__ xT)
{
    const int y = blockIdx.x;
    const int b = blockIdx.y;
    __shared__ float lt[64 * 129];          // 33,024 B, pad 129 kills conflicts
    #pragma unroll
    for (int t = 0; t < 8; ++t) {
        int idx = threadIdx.x + t * 256;    // (c, x-quad)
        int c  = idx >> 5;
        int x4 = (idx & 31) * 4;
        f32x4 v = *(const f32x4*)&x[(((size_t)b * CIN + c) * H + y) * W + x4];
        lt[c * 129 + x4 + 0] = v.x;
        lt[c * 129 + x4 + 1] = v.y;
        lt[c * 129 + x4 + 2] = v.z;
        lt[c * 129 + x4 + 3] = v.w;
    }
    __syncthreads();
    #pragma unroll
    for (int t = 0; t < 8; ++t) {
        int idx = threadIdx.x + t * 256;    // (xp, c-quad)
        int xp = idx >> 4;
        int c4 = (idx & 15) * 4;
        f32x4 v = { lt[(c4 + 0) * 129 + xp], lt[(c4 + 1) * 129 + xp],
                    lt[(c4 + 2) * 129 + xp], lt[(c4 + 3) * 129 + xp] };
        *(f32x4*)&xT[(((size_t)b * H + y) * W + xp) * CIN + c4] = v;
    }
}

// ---------------------------------------------------------------------------
// offmask: 27-filter 3x3 conv. Block = 64 px (32 f x 8 pg of 8 px).
// This round: LDS reads widened. lx base shifted so xr = b128+b128+b64
// (3 reads vs 30); weights from wtap2 [c][f][12] = b128+b128+b32 (3 vs 9).
// ---------------------------------------------------------------------------
#define CC 8
__global__ __launch_bounds__(256) void offmask_kernel(
    const float* __restrict__ x, const float* __restrict__ wtap2,
    const float* __restrict__ bcat, float* __restrict__ offs,
    float* __restrict__ mask)
{
    const int wo0 = blockIdx.x * 64;
    const int ho  = blockIdx.y;
    const int b   = blockIdx.z;
    const int tid = threadIdx.x;
    const int f   = tid & 31;
    const int pg  = tid >> 5;
    const int px0 = pg * 8;

    __shared__ float lx[CC * 3 * 72];     // 6,912 B (base x = wo0-1)
    __shared__ float lw2[CC * 32 * 12];   // 12,288 B

    float acc[8];
    #pragma unroll
    for (int i = 0; i < 8; ++i) acc[i] = 0.f;

    const float* xb = x + b * CIN * HW;

    for (int cb = 0; cb < CIN; cb += CC) {
        if (cb) __syncthreads();
        #pragma unroll
        for (int i = 0; i < 7; ++i) {
            int idx = tid + i * 256;
            if (idx < CC * 3 * 72) {
                int c  = idx / 216;
                int rem = idx % 216;
                int ry = rem / 72;
                int j  = rem % 72;
                int g  = wo0 - 1 + j;
                int y  = ho - 1 + ry;
                float v = (y >= 0 && y < H && g >= 0 && g < W)
                          ? xb[(cb + c) * HW + y * W + g] : 0.f;
                lx[idx] = v;
            }
        }
        #pragma unroll
        for (int i = 0; i < 12; ++i) {
            int idx = tid + i * 256;
            lw2[idx] = wtap2[cb * (32 * 12) + idx];
        }
        __syncthreads();
        #pragma unroll 1
        for (int c = 0; c < CC; ++c) {
            const float* wrow = &lw2[(c * 32 + f) * 12];
            f32x4 wq0 = *(const f32x4*)wrow;
            f32x4 wq1 = *(const f32x4*)(wrow + 4);
            float wv[9] = {wq0.x, wq0.y, wq0.z, wq0.w,
                           wq1.x, wq1.y, wq1.z, wq1.w, wrow[8]};
            float xr[3][10];
            #pragma unroll
            for (int q = 0; q < 3; ++q) {
                const float* xrow = &lx[(c * 3 + q) * 72 + px0];
                f32x4 xa = *(const f32x4*)xrow;
                f32x4 xb4 = *(const f32x4*)(xrow + 4);
                f32x2 xc = *(const f32x2*)(xrow + 8);
                xr[q][0] = xa.x;  xr[q][1] = xa.y;  xr[q][2] = xa.z;  xr[q][3] = xa.w;
                xr[q][4] = xb4.x; xr[q][5] = xb4.y; xr[q][6] = xb4.z; xr[q][7] = xb4.w;
                xr[q][8] = xc.x;  xr[q][9] = xc.y;
            }
            #pragma unroll
            for (int ky = 0; ky < 3; ++ky) {
                #pragma unroll
                for (int kx = 0; kx < 3; ++kx) {
                    float w = wv[ky * 3 + kx];
                    #pragma unroll
                    for (int p = 0; p < 8; ++p)
                        acc[p] += xr[ky][p + kx] * w;
                }
            }
        }
    }

    const float bv = bcat[f];
    if (f < 18) {
        float* op = offs + ((b * 18 + f) * H + ho) * W + wo0 + px0;
        #pragma unroll
        for (int p = 0; p < 8; ++p) op[p] = acc[p] + bv;
    } else if (f < 27) {
        float* mp = mask + ((b * 9 + (f - 18)) * H + ho) * W + wo0 + px0;
        #pragma unroll
        for (int p = 0; p < 8; ++p) {
            float a = acc[p] + bv;
            mp[p] = 1.f / (1.f + expf(-a));
        }
    }
}

// ---------------------------------------------------------------------------
// deform2 (NHWC): fused bilinear-sample + MFMA einsum.
// Gather reads xT: per slot per cb, 16x dwordx4 (4 corners x 16 ch) issued
// as a forced batch (volatile asm + single vmcnt(0) + sched_barrier).
// ---------------------------------------------------------------------------
__global__ __launch_bounds__(256, 4) void deform2_kernel(
    const float* __restrict__ xT, const float* __restrict__ offs,
    const float* __restrict__ maskp, const short* __restrict__ wbf,
    float* __restrict__ out)
{
    const int half = blockIdx.x;
    const int ho   = blockIdx.y;
    const int b    = blockIdx.z;
    const int wo0  = half * 64;
    const int tid  = threadIdx.x;
    const int lane = tid & 63;
    const int wv   = tid >> 6;
    const int oh   = (wv & 1) * 64;
    const int ph   = (wv >> 1) * 32;
    const int row16 = lane & 15, kq = lane >> 4;

    __shared__ __align__(16) short S[64 * LDK];   // 21,504 B

    if (tid < 128) {                      // zero K-pad [144,160) once
        short8 z = {0,0,0,0,0,0,0,0};
        *(short8*)&S[(tid >> 1) * LDK + 144 + (tid & 1) * 8] = z;
    }

    // ---- metadata: slot s = tid + j*256 -> (tap k = s>>6, px p = s&63) ----
    int   moff[3][2];                      // float offsets of corner pixels
    float wA0[3], wB0[3], wA1[3], wB1[3];
    #pragma unroll
    for (int j = 0; j < 3; ++j) {
        moff[j][0] = 0; moff[j][1] = 0;
        wA0[j] = 0.f; wB0[j] = 0.f; wA1[j] = 0.f; wB1[j] = 0.f;
        int s = tid + j * 256;
        if (s < 576) {
            int k = s >> 6, p = s & 63;
            int wo = wo0 + p;
            int ky = k / 3, kx = k % 3;
            int obase = ((b * 18 + 2 * k) * H + ho) * W + wo;
            float dy = offs[obase];
            float dx = offs[obase + HW];
            float mk = maskp[((b * 9 + k) * H + ho) * W + wo];
            float py  = (float)(ho - 1 + ky) + dy;
            float pxf = (float)(wo - 1 + kx) + dx;
            float fy = floorf(py), fx = floorf(pxf);
            float ly = py - fy, lx = pxf - fx;
            int y0 = (int)fy, x0 = (int)fx;
            int y1 = y0 + 1,  x1 = x0 + 1;
            bool vy0 = (y0 >= 0) && (y0 < H);
            bool vy1 = (y1 >= 0) && (y1 < H);
            bool vx0 = (x0 >= 0) && (x0 < W);
            bool vx1 = (x1 >= 0) && (x1 < W);
            float w0 = (vy0 && vx0) ? (1.f - ly) * (1.f - lx) * mk : 0.f;
            float w1 = (vy0 && vx1) ? (1.f - ly) * lx * mk : 0.f;
            float w2 = (vy1 && vx0) ? ly * (1.f - lx) * mk : 0.f;
            float w3 = (vy1 && vx1) ? ly * lx * mk : 0.f;
            int lc = min(max(x0, 0), W - 2);
            bool sel = (x0 == lc);
            int r0 = min(max(y0, 0), H - 1);
            int r1 = min(max(y1, 0), H - 1);
            moff[j][0] = (r0 * W + lc) * CIN;
            moff[j][1] = (r1 * W + lc) * CIN;
            wA0[j] = sel ? w0 : w1;  wB0[j] = sel ? w1 : w0;
            wA1[j] = sel ? w2 : w3;  wB1[j] = sel ? w3 : w2;
        }
    }

    f32x4 acc[4][2];
    #pragma unroll
    for (int i = 0; i < 4; ++i)
        #pragma unroll
        for (int j = 0; j < 2; ++j)
            acc[i][j] = (f32x4){0.f, 0.f, 0.f, 0.f};

    const float* xTb = xT + (size_t)b * HW * CIN;

    #pragma unroll 1
    for (int cb = 0; cb < 4; ++cb) {
        // ---- gather: 4 corners x 16 contiguous channels, forced batch ----
        #pragma unroll
        for (int j = 0; j < 3; ++j) {
            int s = tid + j * 256;
            if (s < 576) {
                int k = s >> 6, p = s & 63;
                const float* b0p = xTb + moff[j][0] + cb * 16;
                const float* b1p = xTb + moff[j][1] + cb * 16;
                f32x4 a0q0, a0q1, a0q2, a0q3;    // corner (r0, lc)
                f32x4 a1q0, a1q1, a1q2, a1q3;    // corner (r0, lc+1): +256B
                f32x4 c0q0, c0q1, c0q2, c0q3;    // corner (r1, lc)
                f32x4 c1q0, c1q1, c1q2, c1q3;    // corner (r1, lc+1)
                GL16(a0q0, b0p, 0);   GL16(a0q1, b0p, 16);
                GL16(a0q2, b0p, 32);  GL16(a0q3, b0p, 48);
                GL16(a1q0, b0p, 256); GL16(a1q1, b0p, 272);
                GL16(a1q2, b0p, 288); GL16(a1q3, b0p, 304);
                GL16(c0q0, b1p, 0);   GL16(c0q1, b1p, 16);
                GL16(c0q2, b1p, 32);  GL16(c0q3, b1p, 48);
                GL16(c1q0, b1p, 256); GL16(c1q1, b1p, 272);
                GL16(c1q2, b1p, 288); GL16(c1q3, b1p, 304);
                asm volatile("s_waitcnt vmcnt(0)" ::: "memory");
                __builtin_amdgcn_sched_barrier(0);
                float wa0 = wA0[j], wb0 = wB0[j], wa1 = wA1[j], wb1 = wB1[j];
                f32x4 v0 = wa0 * a0q0 + wb0 * a1q0 + wa1 * c0q0 + wb1 * c1q0;
                f32x4 v1 = wa0 * a0q1 + wb0 * a1q1 + wa1 * c0q1 + wb1 * c1q1;
                f32x4 v2 = wa0 * a0q2 + wb0 * a1q2 + wa1 * c0q2 + wb1 * c1q2;
                f32x4 v3 = wa0 * a0q3 + wb0 * a1q3 + wa1 * c0q3 + wb1 * c1q3;
                short8 lo, hi;
                lo[0] = (short)f2bf(v0.x); lo[1] = (short)f2bf(v0.y);
                lo[2] = (short)f2bf(v0.z); lo[3] = (short)f2bf(v0.w);
                lo[4] = (short)f2bf(v1.x); lo[5] = (short)f2bf(v1.y);
                lo[6] = (short)f2bf(v1.z); lo[7] = (short)f2bf(v1.w);
                hi[0] = (short)f2bf(v2.x); hi[1] = (short)f2bf(v2.y);
                hi[2] = (short)f2bf(v2.z); hi[3] = (short)f2bf(v2.w);
                hi[4] = (short)f2bf(v3.x); hi[5] = (short)f2bf(v3.y);
                hi[6] = (short)f2bf(v3.z); hi[7] = (short)f2bf(v3.w);
                *(short8*)&S[p * LDK + k * 16]     = lo;
                *(short8*)&S[p * LDK + k * 16 + 8] = hi;
            }
        }
        __syncthreads();
        // ---- MFMA: K=160 (5 steps of 32) ----
        #pragma unroll
        for (int ks = 0; ks < 5; ++ks) {
            short8 a[4];
            #pragma unroll
            for (int of = 0; of < 4; ++of) {
                int o = oh + of * 16 + row16;
                a[of] = *(const short8*)(wbf + o * WBF_COLS + cb * 160 + ks * 32 + kq * 8);
            }
            #pragma unroll
            for (int pf = 0; pf < 2; ++pf) {
                int p = ph + pf * 16 + row16;
                short8 bfr = *(const short8*)&S[p * LDK + ks * 32 + kq * 8];
                #pragma unroll
                for (int of = 0; of < 4; ++of)
                    acc[of][pf] = __builtin_amdgcn_mfma_f32_16x16x32_bf16(
                        a[of], bfr, acc[of][pf], 0, 0, 0);
            }
        }
        __syncthreads();
    }

    // ---- store: C/D layout col(px)=lane&15, row(o)=(lane>>4)*4+r ----
    #pragma unroll
    for (int of = 0; of < 4; ++of) {
        #pragma unroll
        for (int r = 0; r < 4; ++r) {
            int o = oh + of * 16 + kq * 4 + r;
            float* orow = out + ((b * COUT + o) * H + ho) * W;
            #pragma unroll
            for (int pf = 0; pf < 2; ++pf) {
                int wo = wo0 + ph + pf * 16 + row16;
                orow[wo] = acc[of][pf][r];
            }
        }
    }
}

// ---------------------------------------------------------------------------
// deform2_fb: fallback (NCHW gather) if workspace can't hold xT. Identical to
// the previously-verified kernel.
// ---------------------------------------------------------------------------
__global__ __launch_bounds__(256, 4) void deform2_fb(
    const float* __restrict__ x, const float* __restrict__ offs,
    const float* __restrict__ maskp, const short* __restrict__ wbf,
    float* __restrict__ out)
{
    const int half = blockIdx.x;
    const int ho   = blockIdx.y;
    const int b    = blockIdx.z;
    const int wo0  = half * 64;
    const int tid  = threadIdx.x;
    const int lane = tid & 63;
    const int wv   = tid >> 6;
    const int oh   = (wv & 1) * 64;
    const int ph   = (wv >> 1) * 32;
    const int row16 = lane & 15, kq = lane >> 4;

    __shared__ __align__(16) short S[64 * LDK];

    if (tid < 128) {
        short8 z = {0,0,0,0,0,0,0,0};
        *(short8*)&S[(tid >> 1) * LDK + 144 + (tid & 1) * 8] = z;
    }

    int   moff[3][2];
    float wA0[3], wB0[3], wA1[3], wB1[3];
    #pragma unroll
    for (int j = 0; j < 3; ++j) {
        moff[j][0] = 0; moff[j][1] = 0;
        wA0[j] = 0.f; wB0[j] = 0.f; wA1[j] = 0.f; wB1[j] = 0.f;
        int s = tid + j * 256;
        if (s < 576) {
            int k = s >> 6, p = s & 63;
            int wo = wo0 + p;
            int ky = k / 3, kx = k % 3;
            int obase = ((b * 18 + 2 * k) * H + ho) * W + wo;
            float dy = offs[obase];
            float dx = offs[obase + HW];
            float mk = maskp[((b * 9 + k) * H + ho) * W + wo];
            float py  = (float)(ho - 1 + ky) + dy;
            float pxf = (float)(wo - 1 + kx) + dx;
            float fy = floorf(py), fx = floorf(pxf);
            float ly = py - fy, lx = pxf - fx;
            int y0 = (int)fy, x0 = (int)fx;
            int y1 = y0 + 1,  x1 = x0 + 1;
            bool vy0 = (y0 >= 0) && (y0 < H);
            bool vy1 = (y1 >= 0) && (y1 < H);
            bool vx0 = (x0 >= 0) && (x0 < W);
            bool vx1 = (x1 >= 0) && (x1 < W);
            float w0 = (vy0 && vx0) ? (1.f - ly) * (1.f - lx) * mk : 0.f;
            float w1 = (vy0 && vx1) ? (1.f - ly) * lx * mk : 0.f;
            float w2 = (vy1 && vx0) ? ly * (1.f - lx) * mk : 0.f;
            float w3 = (vy1 && vx1) ? ly * lx * mk : 0.f;
            int lc = min(max(x0, 0), W - 2);
            bool sel = (x0 == lc);
            int r0 = min(max(y0, 0), H - 1);
            int r1 = min(max(y1, 0), H - 1);
            moff[j][0] = (r0 * W + lc) * 4;
            moff[j][1] = (r1 * W + lc) * 4;
            wA0[j] = sel ? w0 : w1;  wB0[j] = sel ? w1 : w0;
            wA1[j] = sel ? w2 : w3;  wB1[j] = sel ? w3 : w2;
        }
    }

    f32x4 acc[4][2];
    #pragma unroll
    for (int i = 0; i < 4; ++i)
        #pragma unroll
        for (int j = 0; j < 2; ++j)
            acc[i][j] = (f32x4){0.f, 0.f, 0.f, 0.f};

    const char* xbc = (const char*)(x + b * CIN * HW);

    #pragma unroll 1
    for (int cb = 0; cb < 4; ++cb) {
        #pragma unroll
        for (int j = 0; j < 3; ++j) {
            int s = tid + j * 256;
            if (s < 576) {
                int k = s >> 6, p = s & 63;
                #pragma unroll
                for (int h2 = 0; h2 < 2; ++h2) {
                    const char* pcb = xbc + (size_t)(cb * 16 + h2 * 8) * (HW * 4);
                    f32x2 ra[8], rb[8];
                    #pragma unroll
                    for (int ci = 0; ci < 8; ++ci) {
                        const char* pc = pcb + (size_t)ci * (HW * 4);
                        ra[ci] = *(const f32x2a*)(pc + moff[j][0]);
                        rb[ci] = *(const f32x2a*)(pc + moff[j][1]);
                    }
                    short8 s8;
                    #pragma unroll
                    for (int ci = 0; ci < 8; ++ci) {
                        float v = wA0[j] * ra[ci].x + wB0[j] * ra[ci].y
                                + wA1[j] * rb[ci].x + wB1[j] * rb[ci].y;
                        s8[ci] = (short)f2bf(v);
                    }
                    *(short8*)&S[p * LDK + k * 16 + h2 * 8] = s8;
                }
            }
        }
        __syncthreads();
        #pragma unroll
        for (int ks = 0; ks < 5; ++ks) {
            short8 a[4];
            #pragma unroll
            for (int of = 0; of < 4; ++of) {
                int o = oh + of * 16 + row16;
                a[of] = *(const short8*)(wbf + o * WBF_COLS + cb * 160 + ks * 32 + kq * 8);
            }
            #pragma unroll
            for (int pf = 0; pf < 2; ++pf) {
                int p = ph + pf * 16 + row16;
                short8 bfr = *(const short8*)&S[p * LDK + ks * 32 + kq * 8];
                #pragma unroll
                for (int of = 0; of < 4; ++of)
                    acc[of][pf] = __builtin_amdgcn_mfma_f32_16x16x32_bf16(
                        a[of], bfr, acc[of][pf], 0, 0, 0);
            }
        }
        __syncthreads();
    }

    #pragma unroll
    for (int of = 0; of < 4; ++of) {
        #pragma unroll
        for (int r = 0; r < 4; ++r) {
            int o = oh + of * 16 + kq * 4 + r;
            float* orow = out + ((b * COUT + o) * H + ho) * W;
            #pragma unroll
            for (int pf = 0; pf < 2; ++pf) {
                int wo = wo0 + ph + pf * 16 + row16;
                orow[wo] = acc[of][pf][r];
            }
        }
    }
}

// ---------------------------------------------------------------------------
extern "C" void kernel_launch(void* const* d_in, const int* in_sizes, int n_in,
                              void* d_out, int out_size, void* d_ws, size_t ws_size,
                              hipStream_t stream)
{
    const float* x      = (const float*)d_in[0];
    const float* w_off  = (const float*)d_in[1];
    const float* b_off  = (const float*)d_in[2];
    const float* w_mask = (const float*)d_in[3];
    const float* b_mask = (const float*)d_in[4];
    const float* weight = (const float*)d_in[5];
    float* out   = (float*)d_out;

    float* offs  = (float*)d_ws;
    float* maskb = offs + OFFS_SZ;
    float* bcat  = maskb + MASK_SZ;
    short* wbf   = (short*)(bcat + 32);
    float* wtap2 = bcat + 32 + WBF_SHORTS / 2;
    float* xT    = wtap2 + WTAP2_SZ;

    size_t need = ((size_t)OFFS_SZ + MASK_SZ + 32 + WBF_SHORTS / 2 + WTAP2_SZ
                   + XT_SZ) * 4;

    prep_kernel<<<dim3((WTAP2_SZ + 255) / 256), 256, 0, stream>>>(
        w_off, b_off, w_mask, b_mask, wtap2, bcat);
    prep_wbf<<<dim3((WBF_SHORTS + 255) / 256), 256, 0, stream>>>(weight, wbf);

    if (ws_size >= need) {
        xpose_kernel<<<dim3(H, B), 256, 0, stream>>>(x, xT);
        offmask_kernel<<<dim3(2, H, B), 256, 0, stream>>>(x, wtap2, bcat, offs, maskb);
        deform2_kernel<<<dim3(2, H, B), 256, 0, stream>>>(xT, offs, maskb, wbf, out);
    } else {
        offmask_kernel<<<dim3(2, H, B), 256, 0, stream>>>(x, wtap2, bcat, offs, maskb);
        deform2_fb<<<dim3(2, H, B), 256, 0, stream>>>(x, offs, maskb, wbf, out);
    }
}

// Round 3
// 201.609 us; speedup vs baseline: 1.0332x; 1.0332x over previous
//
#include <hip/hip_runtime.h>
#include <math.h>

#define B 4
#define CIN 64
#define H 128
#define W 128
#define COUT 128
#define KK 9
#define HW (H*W)

#define OFFS_SZ (B*18*HW)
#define MASK_SZ (B*9*HW)
#define WTAP2_SZ (CIN*32*12)
#define WBF_COLS 640                 // 4 chunks x 160 (144 real + 16 zero)
#define WBF_SHORTS (COUT*WBF_COLS)
#define XT_SZ (B*HW*CIN)
#define LDK 168                      // LDS k-stride (shorts); 336B row stride

typedef __attribute__((ext_vector_type(8))) short short8;
typedef __attribute__((ext_vector_type(4))) float f32x4;
typedef __attribute__((ext_vector_type(2))) float f32x2;
typedef f32x2 __attribute__((aligned(4))) f32x2a;   // align-4 float2 load

// batched gather load: volatile asm guarantees the load is issued (not
// serialized into a load->wait->use chain by the scheduler).
#define GL16(dst, ptr, OFF) \
    asm volatile("global_load_dwordx4 %0, %1, off offset:" #OFF \
                 : "=v"(dst) : "v"(ptr))

__device__ __forceinline__ unsigned short f2bf(float f) {
    unsigned int u = __float_as_uint(f);
    u += 0x7fffu + ((u >> 16) & 1u);
    return (unsigned short)(u >> 16);
}

// ---------------------------------------------------------------------------
// prep: wtap2[c][f][12] (offmask weights, t-contiguous for b128 LDS reads),
// bcat biases.
// ---------------------------------------------------------------------------
__global__ void prep_kernel(const float* __restrict__ w_off, const float* __restrict__ b_off,
                            const float* __restrict__ w_mask, const float* __restrict__ b_mask,
                            float* __restrict__ wtap2, float* __restrict__ bcat)
{
    int idx = blockIdx.x * 256 + threadIdx.x;
    if (idx < WTAP2_SZ) {
        int t = idx % 12;
        int f = (idx / 12) & 31;
        int c = idx / 384;
        float v = 0.f;
        if (t < 9) {
            if (f < 18)      v = w_off[(f * CIN + c) * 9 + t];
            else if (f < 27) v = w_mask[((f - 18) * CIN + c) * 9 + t];
        }
        wtap2[idx] = v;
    }
    if (blockIdx.x == 0 && threadIdx.x < 32) {
        int f = threadIdx.x;
        float bv = 0.f;
        if (f < 18) bv = b_off[f];
        else if (f < 27) bv = b_mask[f - 18];
        bcat[f] = bv;
    }
}

// ---------------------------------------------------------------------------
// prep_wbf: einsum weights -> bf16, layout [o][cb*160 + tap*16 + ci];
// pad cols [144,160) per chunk are ZERO.
// ---------------------------------------------------------------------------
__global__ void prep_wbf(const float* __restrict__ wgt, short* __restrict__ wbf)
{
    int idx = blockIdx.x * 256 + threadIdx.x;
    if (idx >= WBF_SHORTS) return;
    int o  = idx / WBF_COLS;
    int kp = idx % WBF_COLS;
    int cb = kp / 160, r = kp % 160;
    float v = 0.f;
    if (r < 144) {
        int tap = r >> 4;
        int c   = cb * 16 + (r & 15);
        v = wgt[(o * CIN + c) * KK + tap];
    }
    wbf[idx] = (short)f2bf(v);
}

// ---------------------------------------------------------------------------
// XCD band swizzle: blocks are dispatched round-robin over 8 XCDs
// (xcd = bid % 8, measured m09). Map so XCD i owns a CONTIGUOUS band of
// tiles: T = (bid % 8) * (n/8) + bid / 8. All spatial kernels use the SAME
// band layout so producer (offmask/xpose) and consumer (deform2) share L2.
// Band working set (64 rows, one image): x 2 MB + xT 2.1 MB + offs/mask
// 0.9 MB -> fits the 4 MB per-XCD L2.
// ---------------------------------------------------------------------------

// ---------------------------------------------------------------------------
// xpose: x NCHW f32 -> xT NHWC f32 (xT[b][y][xp][c], c fastest).
// Block = one (b,y) row: 128 px x 64 ch staged through padded LDS.
// Grid 512 (flat, swizzled): XCD i gets y-band [64*(i%2), ...) of image i/2.
// ---------------------------------------------------------------------------
__global__ __launch_bounds__(256) void xpose_kernel(const float* __restrict__ x,
                                                    float* __restrict__ xT)
{
    const int bid = blockIdx.x;
    const int T = (bid & 7) * 64 + (bid >> 3);
    const int y = T & 127;
    const int b = T >> 7;
    __shared__ float lt[64 * 129];          // 33,024 B, pad 129 kills conflicts
    #pragma unroll
    for (int t = 0; t < 8; ++t) {
        int idx = threadIdx.x + t * 256;    // (c, x-quad)
        int c  = idx >> 5;
        int x4 = (idx & 31) * 4;
        f32x4 v = *(const f32x4*)&x[(((size_t)b * CIN + c) * H + y) * W + x4];
        lt[c * 129 + x4 + 0] = v.x;
        lt[c * 129 + x4 + 1] = v.y;
        lt[c * 129 + x4 + 2] = v.z;
        lt[c * 129 + x4 + 3] = v.w;
    }
    __syncthreads();
    #pragma unroll
    for (int t = 0; t < 8; ++t) {
        int idx = threadIdx.x + t * 256;    // (xp, c-quad)
        int xp = idx >> 4;
        int c4 = (idx & 15) * 4;
        f32x4 v = { lt[(c4 + 0) * 129 + xp], lt[(c4 + 1) * 129 + xp],
                    lt[(c4 + 2) * 129 + xp], lt[(c4 + 3) * 129 + xp] };
        *(f32x4*)&xT[(((size_t)b * H + y) * W + xp) * CIN + c4] = v;
    }
}

// ---------------------------------------------------------------------------
// offmask: 27-filter 3x3 conv. Block = 64 px (32 f x 8 pg of 8 px).
// Grid 1024 (flat, swizzled to match deform2's bands).
// ---------------------------------------------------------------------------
#define CC 8
__global__ __launch_bounds__(256) void offmask_kernel(
    const float* __restrict__ x, const float* __restrict__ wtap2,
    const float* __restrict__ bcat, float* __restrict__ offs,
    float* __restrict__ mask)
{
    const int bid = blockIdx.x;
    const int T = (bid & 7) * 128 + (bid >> 3);
    const int wo0 = (T & 1) * 64;
    const int ho  = (T >> 1) & 127;
    const int b   = T >> 8;
    const int tid = threadIdx.x;
    const int f   = tid & 31;
    const int pg  = tid >> 5;
    const int px0 = pg * 8;

    __shared__ float lx[CC * 3 * 72];     // 6,912 B (base x = wo0-1)
    __shared__ float lw2[CC * 32 * 12];   // 12,288 B

    float acc[8];
    #pragma unroll
    for (int i = 0; i < 8; ++i) acc[i] = 0.f;

    const float* xb = x + b * CIN * HW;

    for (int cb = 0; cb < CIN; cb += CC) {
        if (cb) __syncthreads();
        #pragma unroll
        for (int i = 0; i < 7; ++i) {
            int idx = tid + i * 256;
            if (idx < CC * 3 * 72) {
                int c  = idx / 216;
                int rem = idx % 216;
                int ry = rem / 72;
                int j  = rem % 72;
                int g  = wo0 - 1 + j;
                int y  = ho - 1 + ry;
                float v = (y >= 0 && y < H && g >= 0 && g < W)
                          ? xb[(cb + c) * HW + y * W + g] : 0.f;
                lx[idx] = v;
            }
        }
        #pragma unroll
        for (int i = 0; i < 12; ++i) {
            int idx = tid + i * 256;
            lw2[idx] = wtap2[cb * (32 * 12) + idx];
        }
        __syncthreads();
        #pragma unroll 1
        for (int c = 0; c < CC; ++c) {
            const float* wrow = &lw2[(c * 32 + f) * 12];
            f32x4 wq0 = *(const f32x4*)wrow;
            f32x4 wq1 = *(const f32x4*)(wrow + 4);
            float wv[9] = {wq0.x, wq0.y, wq0.z, wq0.w,
                           wq1.x, wq1.y, wq1.z, wq1.w, wrow[8]};
            float xr[3][10];
            #pragma unroll
            for (int q = 0; q < 3; ++q) {
                const float* xrow = &lx[(c * 3 + q) * 72 + px0];
                f32x4 xa = *(const f32x4*)xrow;
                f32x4 xb4 = *(const f32x4*)(xrow + 4);
                f32x2 xc = *(const f32x2*)(xrow + 8);
                xr[q][0] = xa.x;  xr[q][1] = xa.y;  xr[q][2] = xa.z;  xr[q][3] = xa.w;
                xr[q][4] = xb4.x; xr[q][5] = xb4.y; xr[q][6] = xb4.z; xr[q][7] = xb4.w;
                xr[q][8] = xc.x;  xr[q][9] = xc.y;
            }
            #pragma unroll
            for (int ky = 0; ky < 3; ++ky) {
                #pragma unroll
                for (int kx = 0; kx < 3; ++kx) {
                    float w = wv[ky * 3 + kx];
                    #pragma unroll
                    for (int p = 0; p < 8; ++p)
                        acc[p] += xr[ky][p + kx] * w;
                }
            }
        }
    }

    const float bv = bcat[f];
    if (f < 18) {
        float* op = offs + ((b * 18 + f) * H + ho) * W + wo0 + px0;
        #pragma unroll
        for (int p = 0; p < 8; ++p) op[p] = acc[p] + bv;
    } else if (f < 27) {
        float* mp = mask + ((b * 9 + (f - 18)) * H + ho) * W + wo0 + px0;
        #pragma unroll
        for (int p = 0; p < 8; ++p) {
            float a = acc[p] + bv;
            mp[p] = 1.f / (1.f + expf(-a));
        }
    }
}

// ---------------------------------------------------------------------------
// deform2 (NHWC): fused bilinear-sample + MFMA einsum.
// Gather reads xT: per slot per cb, 16x dwordx4 (4 corners x 16 ch) issued
// as a forced batch. Grid 1024 (flat, swizzled): same bands as xpose/offmask
// -> xT, offs, mask served from the local XCD's L2.
// ---------------------------------------------------------------------------
__global__ __launch_bounds__(256, 4) void deform2_kernel(
    const float* __restrict__ xT, const float* __restrict__ offs,
    const float* __restrict__ maskp, const short* __restrict__ wbf,
    float* __restrict__ out)
{
    const int bid = blockIdx.x;
    const int T = (bid & 7) * 128 + (bid >> 3);
    const int wo0 = (T & 1) * 64;
    const int ho  = (T >> 1) & 127;
    const int b   = T >> 8;
    const int tid  = threadIdx.x;
    const int lane = tid & 63;
    const int wv   = tid >> 6;
    const int oh   = (wv & 1) * 64;
    const int ph   = (wv >> 1) * 32;
    const int row16 = lane & 15, kq = lane >> 4;

    __shared__ __align__(16) short S[64 * LDK];   // 21,504 B

    if (tid < 128) {                      // zero K-pad [144,160) once
        short8 z = {0,0,0,0,0,0,0,0};
        *(short8*)&S[(tid >> 1) * LDK + 144 + (tid & 1) * 8] = z;
    }

    // ---- metadata: slot s = tid + j*256 -> (tap k = s>>6, px p = s&63) ----
    int   moff[3][2];                      // float offsets of corner pixels
    float wA0[3], wB0[3], wA1[3], wB1[3];
    #pragma unroll
    for (int j = 0; j < 3; ++j) {
        moff[j][0] = 0; moff[j][1] = 0;
        wA0[j] = 0.f; wB0[j] = 0.f; wA1[j] = 0.f; wB1[j] = 0.f;
        int s = tid + j * 256;
        if (s < 576) {
            int k = s >> 6, p = s & 63;
            int wo = wo0 + p;
            int ky = k / 3, kx = k % 3;
            int obase = ((b * 18 + 2 * k) * H + ho) * W + wo;
            float dy = offs[obase];
            float dx = offs[obase + HW];
            float mk = maskp[((b * 9 + k) * H + ho) * W + wo];
            float py  = (float)(ho - 1 + ky) + dy;
            float pxf = (float)(wo - 1 + kx) + dx;
            float fy = floorf(py), fx = floorf(pxf);
            float ly = py - fy, lx = pxf - fx;
            int y0 = (int)fy, x0 = (int)fx;
            int y1 = y0 + 1,  x1 = x0 + 1;
            bool vy0 = (y0 >= 0) && (y0 < H);
            bool vy1 = (y1 >= 0) && (y1 < H);
            bool vx0 = (x0 >= 0) && (x0 < W);
            bool vx1 = (x1 >= 0) && (x1 < W);
            float w0 = (vy0 && vx0) ? (1.f - ly) * (1.f - lx) * mk : 0.f;
            float w1 = (vy0 && vx1) ? (1.f - ly) * lx * mk : 0.f;
            float w2 = (vy1 && vx0) ? ly * (1.f - lx) * mk : 0.f;
            float w3 = (vy1 && vx1) ? ly * lx * mk : 0.f;
            int lc = min(max(x0, 0), W - 2);
            bool sel = (x0 == lc);
            int r0 = min(max(y0, 0), H - 1);
            int r1 = min(max(y1, 0), H - 1);
            moff[j][0] = (r0 * W + lc) * CIN;
            moff[j][1] = (r1 * W + lc) * CIN;
            wA0[j] = sel ? w0 : w1;  wB0[j] = sel ? w1 : w0;
            wA1[j] = sel ? w2 : w3;  wB1[j] = sel ? w3 : w2;
        }
    }

    f32x4 acc[4][2];
    #pragma unroll
    for (int i = 0; i < 4; ++i)
        #pragma unroll
        for (int j = 0; j < 2; ++j)
            acc[i][j] = (f32x4){0.f, 0.f, 0.f, 0.f};

    const float* xTb = xT + (size_t)b * HW * CIN;

    #pragma unroll 1
    for (int cb = 0; cb < 4; ++cb) {
        // ---- gather: 4 corners x 16 contiguous channels, forced batch ----
        #pragma unroll
        for (int j = 0; j < 3; ++j) {
            int s = tid + j * 256;
            if (s < 576) {
                int k = s >> 6, p = s & 63;
                const float* b0p = xTb + moff[j][0] + cb * 16;
                const float* b1p = xTb + moff[j][1] + cb * 16;
                f32x4 a0q0, a0q1, a0q2, a0q3;    // corner (r0, lc)
                f32x4 a1q0, a1q1, a1q2, a1q3;    // corner (r0, lc+1): +256B
                f32x4 c0q0, c0q1, c0q2, c0q3;    // corner (r1, lc)
                f32x4 c1q0, c1q1, c1q2, c1q3;    // corner (r1, lc+1)
                GL16(a0q0, b0p, 0);   GL16(a0q1, b0p, 16);
                GL16(a0q2, b0p, 32);  GL16(a0q3, b0p, 48);
                GL16(a1q0, b0p, 256); GL16(a1q1, b0p, 272);
                GL16(a1q2, b0p, 288); GL16(a1q3, b0p, 304);
                GL16(c0q0, b1p, 0);   GL16(c0q1, b1p, 16);
                GL16(c0q2, b1p, 32);  GL16(c0q3, b1p, 48);
                GL16(c1q0, b1p, 256); GL16(c1q1, b1p, 272);
                GL16(c1q2, b1p, 288); GL16(c1q3, b1p, 304);
                asm volatile("s_waitcnt vmcnt(0)" ::: "memory");
                __builtin_amdgcn_sched_barrier(0);
                float wa0 = wA0[j], wb0 = wB0[j], wa1 = wA1[j], wb1 = wB1[j];
                f32x4 v0 = wa0 * a0q0 + wb0 * a1q0 + wa1 * c0q0 + wb1 * c1q0;
                f32x4 v1 = wa0 * a0q1 + wb0 * a1q1 + wa1 * c0q1 + wb1 * c1q1;
                f32x4 v2 = wa0 * a0q2 + wb0 * a1q2 + wa1 * c0q2 + wb1 * c1q2;
                f32x4 v3 = wa0 * a0q3 + wb0 * a1q3 + wa1 * c0q3 + wb1 * c1q3;
                short8 lo, hi;
                lo[0] = (short)f2bf(v0.x); lo[1] = (short)f2bf(v0.y);
                lo[2] = (short)f2bf(v0.z); lo[3] = (short)f2bf(v0.w);
                lo[4] = (short)f2bf(v1.x); lo[5] = (short)f2bf(v1.y);
                lo[6] = (short)f2bf(v1.z); lo[7] = (short)f2bf(v1.w);
                hi[0] = (short)f2bf(v2.x); hi[1] = (short)f2bf(v2.y);
                hi[2] = (short)f2bf(v2.z); hi[3] = (short)f2bf(v2.w);
                hi[4] = (short)f2bf(v3.x); hi[5] = (short)f2bf(v3.y);
                hi[6] = (short)f2bf(v3.z); hi[7] = (short)f2bf(v3.w);
                *(short8*)&S[p * LDK + k * 16]     = lo;
                *(short8*)&S[p * LDK + k * 16 + 8] = hi;
            }
        }
        __syncthreads();
        // ---- MFMA: K=160 (5 steps of 32) ----
        #pragma unroll
        for (int ks = 0; ks < 5; ++ks) {
            short8 a[4];
            #pragma unroll
            for (int of = 0; of < 4; ++of) {
                int o = oh + of * 16 + row16;
                a[of] = *(const short8*)(wbf + o * WBF_COLS + cb * 160 + ks * 32 + kq * 8);
            }
            #pragma unroll
            for (int pf = 0; pf < 2; ++pf) {
                int p = ph + pf * 16 + row16;
                short8 bfr = *(const short8*)&S[p * LDK + ks * 32 + kq * 8];
                #pragma unroll
                for (int of = 0; of < 4; ++of)
                    acc[of][pf] = __builtin_amdgcn_mfma_f32_16x16x32_bf16(
                        a[of], bfr, acc[of][pf], 0, 0, 0);
            }
        }
        __syncthreads();
    }

    // ---- store: C/D layout col(px)=lane&15, row(o)=(lane>>4)*4+r ----
    #pragma unroll
    for (int of = 0; of < 4; ++of) {
        #pragma unroll
        for (int r = 0; r < 4; ++r) {
            int o = oh + of * 16 + kq * 4 + r;
            float* orow = out + ((b * COUT + o) * H + ho) * W;
            #pragma unroll
            for (int pf = 0; pf < 2; ++pf) {
                int wo = wo0 + ph + pf * 16 + row16;
                orow[wo] = acc[of][pf][r];
            }
        }
    }
}

// ---------------------------------------------------------------------------
// deform2_fb: fallback (NCHW gather) if workspace can't hold xT.
// ---------------------------------------------------------------------------
__global__ __launch_bounds__(256, 4) void deform2_fb(
    const float* __restrict__ x, const float* __restrict__ offs,
    const float* __restrict__ maskp, const short* __restrict__ wbf,
    float* __restrict__ out)
{
    const int bid = blockIdx.x;
    const int T = (bid & 7) * 128 + (bid >> 3);
    const int wo0 = (T & 1) * 64;
    const int ho  = (T >> 1) & 127;
    const int b   = T >> 8;
    const int tid  = threadIdx.x;
    const int lane = tid & 63;
    const int wv   = tid >> 6;
    const int oh   = (wv & 1) * 64;
    const int ph   = (wv >> 1) * 32;
    const int row16 = lane & 15, kq = lane >> 4;

    __shared__ __align__(16) short S[64 * LDK];

    if (tid < 128) {
        short8 z = {0,0,0,0,0,0,0,0};
        *(short8*)&S[(tid >> 1) * LDK + 144 + (tid & 1) * 8] = z;
    }

    int   moff[3][2];
    float wA0[3], wB0[3], wA1[3], wB1[3];
    #pragma unroll
    for (int j = 0; j < 3; ++j) {
        moff[j][0] = 0; moff[j][1] = 0;
        wA0[j] = 0.f; wB0[j] = 0.f; wA1[j] = 0.f; wB1[j] = 0.f;
        int s = tid + j * 256;
        if (s < 576) {
            int k = s >> 6, p = s & 63;
            int wo = wo0 + p;
            int ky = k / 3, kx = k % 3;
            int obase = ((b * 18 + 2 * k) * H + ho) * W + wo;
            float dy = offs[obase];
            float dx = offs[obase + HW];
            float mk = maskp[((b * 9 + k) * H + ho) * W + wo];
            float py  = (float)(ho - 1 + ky) + dy;
            float pxf = (float)(wo - 1 + kx) + dx;
            float fy = floorf(py), fx = floorf(pxf);
            float ly = py - fy, lx = pxf - fx;
            int y0 = (int)fy, x0 = (int)fx;
            int y1 = y0 + 1,  x1 = x0 + 1;
            bool vy0 = (y0 >= 0) && (y0 < H);
            bool vy1 = (y1 >= 0) && (y1 < H);
            bool vx0 = (x0 >= 0) && (x0 < W);
            bool vx1 = (x1 >= 0) && (x1 < W);
            float w0 = (vy0 && vx0) ? (1.f - ly) * (1.f - lx) * mk : 0.f;
            float w1 = (vy0 && vx1) ? (1.f - ly) * lx * mk : 0.f;
            float w2 = (vy1 && vx0) ? ly * (1.f - lx) * mk : 0.f;
            float w3 = (vy1 && vx1) ? ly * lx * mk : 0.f;
            int lc = min(max(x0, 0), W - 2);
            bool sel = (x0 == lc);
            int r0 = min(max(y0, 0), H - 1);
            int r1 = min(max(y1, 0), H - 1);
            moff[j][0] = (r0 * W + lc) * 4;
            moff[j][1] = (r1 * W + lc) * 4;
            wA0[j] = sel ? w0 : w1;  wB0[j] = sel ? w1 : w0;
            wA1[j] = sel ? w2 : w3;  wB1[j] = sel ? w3 : w2;
        }
    }

    f32x4 acc[4][2];
    #pragma unroll
    for (int i = 0; i < 4; ++i)
        #pragma unroll
        for (int j = 0; j < 2; ++j)
            acc[i][j] = (f32x4){0.f, 0.f, 0.f, 0.f};

    const char* xbc = (const char*)(x + b * CIN * HW);

    #pragma unroll 1
    for (int cb = 0; cb < 4; ++cb) {
        #pragma unroll
        for (int j = 0; j < 3; ++j) {
            int s = tid + j * 256;
            if (s < 576) {
                int k = s >> 6, p = s & 63;
                #pragma unroll
                for (int h2 = 0; h2 < 2; ++h2) {
                    const char* pcb = xbc + (size_t)(cb * 16 + h2 * 8) * (HW * 4);
                    f32x2 ra[8], rb[8];
                    #pragma unroll
                    for (int ci = 0; ci < 8; ++ci) {
                        const char* pc = pcb + (size_t)ci * (HW * 4);
                        ra[ci] = *(const f32x2a*)(pc + moff[j][0]);
                        rb[ci] = *(const f32x2a*)(pc + moff[j][1]);
                    }
                    short8 s8;
                    #pragma unroll
                    for (int ci = 0; ci < 8; ++ci) {
                        float v = wA0[j] * ra[ci].x + wB0[j] * ra[ci].y
                                + wA1[j] * rb[ci].x + wB1[j] * rb[ci].y;
                        s8[ci] = (short)f2bf(v);
                    }
                    *(short8*)&S[p * LDK + k * 16 + h2 * 8] = s8;
                }
            }
        }
        __syncthreads();
        #pragma unroll
        for (int ks = 0; ks < 5; ++ks) {
            short8 a[4];
            #pragma unroll
            for (int of = 0; of < 4; ++of) {
                int o = oh + of * 16 + row16;
                a[of] = *(const short8*)(wbf + o * WBF_COLS + cb * 160 + ks * 32 + kq * 8);
            }
            #pragma unroll
            for (int pf = 0; pf < 2; ++pf) {
                int p = ph + pf * 16 + row16;
                short8 bfr = *(const short8*)&S[p * LDK + ks * 32 + kq * 8];
                #pragma unroll
                for (int of = 0; of < 4; ++of)
                    acc[of][pf] = __builtin_amdgcn_mfma_f32_16x16x32_bf16(
                        a[of], bfr, acc[of][pf], 0, 0, 0);
            }
        }
        __syncthreads();
    }

    #pragma unroll
    for (int of = 0; of < 4; ++of) {
        #pragma unroll
        for (int r = 0; r < 4; ++r) {
            int o = oh + of * 16 + kq * 4 + r;
            float* orow = out + ((b * COUT + o) * H + ho) * W;
            #pragma unroll
            for (int pf = 0; pf < 2; ++pf) {
                int wo = wo0 + ph + pf * 16 + row16;
                orow[wo] = acc[of][pf][r];
            }
        }
    }
}

// ---------------------------------------------------------------------------
extern "C" void kernel_launch(void* const* d_in, const int* in_sizes, int n_in,
                              void* d_out, int out_size, void* d_ws, size_t ws_size,
                              hipStream_t stream)
{
    const float* x      = (const float*)d_in[0];
    const float* w_off  = (const float*)d_in[1];
    const float* b_off  = (const float*)d_in[2];
    const float* w_mask = (const float*)d_in[3];
    const float* b_mask = (const float*)d_in[4];
    const float* weight = (const float*)d_in[5];
    float* out   = (float*)d_out;

    float* offs  = (float*)d_ws;
    float* maskb = offs + OFFS_SZ;
    float* bcat  = maskb + MASK_SZ;
    short* wbf   = (short*)(bcat + 32);
    float* wtap2 = bcat + 32 + WBF_SHORTS / 2;
    float* xT    = wtap2 + WTAP2_SZ;

    size_t need = ((size_t)OFFS_SZ + MASK_SZ + 32 + WBF_SHORTS / 2 + WTAP2_SZ
                   + XT_SZ) * 4;

    prep_kernel<<<dim3((WTAP2_SZ + 255) / 256), 256, 0, stream>>>(
        w_off, b_off, w_mask, b_mask, wtap2, bcat);
    prep_wbf<<<dim3((WBF_SHORTS + 255) / 256), 256, 0, stream>>>(weight, wbf);

    if (ws_size >= need) {
        // order: offmask first, xpose second -> xT is freshest in L2 when
        // deform2 starts (per-XCD L2 is ~4 MB; band demand ~3 MB).
        offmask_kernel<<<dim3(1024), 256, 0, stream>>>(x, wtap2, bcat, offs, maskb);
        xpose_kernel<<<dim3(512), 256, 0, stream>>>(x, xT);
        deform2_kernel<<<dim3(1024), 256, 0, stream>>>(xT, offs, maskb, wbf, out);
    } else {
        offmask_kernel<<<dim3(1024), 256, 0, stream>>>(x, wtap2, bcat, offs, maskb);
        deform2_fb<<<dim3(1024), 256, 0, stream>>>(x, offs, maskb, wbf, out);
    }
}

// Round 4
// 139.224 us; speedup vs baseline: 1.4962x; 1.4481x over previous
//
#include <hip/hip_runtime.h>
#include <math.h>

#define B 4
#define CIN 64
#define H 128
#define W 128
#define COUT 128
#define KK 9
#define HW (H*W)

#define OFFS_SZ (B*18*HW)
#define MASK_SZ (B*9*HW)
#define WTAP2_SZ (CIN*32*12)
#define WBF_COLS 640                 // 4 chunks x 160 (144 real + 16 zero)
#define WBF_SHORTS (COUT*WBF_COLS)
#define LDK 168                      // LDS k-stride (shorts); 336B row stride

typedef __attribute__((ext_vector_type(8))) short short8;
typedef __attribute__((ext_vector_type(4))) float f32x4;
typedef __attribute__((ext_vector_type(2))) float f32x2;
typedef f32x2 __attribute__((aligned(4))) f32x2a;   // align-4 float2 load

__device__ __forceinline__ unsigned short f2bf(float f) {
    unsigned int u = __float_as_uint(f);
    u += 0x7fffu + ((u >> 16) & 1u);
    return (unsigned short)(u >> 16);
}

// ---------------------------------------------------------------------------
// prep: wtap2[c][f][12] (offmask weights, t-contiguous for b128 LDS reads),
// bcat biases.
// ---------------------------------------------------------------------------
__global__ void prep_kernel(const float* __restrict__ w_off, const float* __restrict__ b_off,
                            const float* __restrict__ w_mask, const float* __restrict__ b_mask,
                            float* __restrict__ wtap2, float* __restrict__ bcat)
{
    int idx = blockIdx.x * 256 + threadIdx.x;
    if (idx < WTAP2_SZ) {
        int t = idx % 12;
        int f = (idx / 12) & 31;
        int c = idx / 384;
        float v = 0.f;
        if (t < 9) {
            if (f < 18)      v = w_off[(f * CIN + c) * 9 + t];
            else if (f < 27) v = w_mask[((f - 18) * CIN + c) * 9 + t];
        }
        wtap2[idx] = v;
    }
    if (blockIdx.x == 0 && threadIdx.x < 32) {
        int f = threadIdx.x;
        float bv = 0.f;
        if (f < 18) bv = b_off[f];
        else if (f < 27) bv = b_mask[f - 18];
        bcat[f] = bv;
    }
}

// ---------------------------------------------------------------------------
// prep_wbf: einsum weights -> bf16, layout [o][cb*160 + tap*16 + ci];
// pad cols [144,160) per chunk are ZERO.
// ---------------------------------------------------------------------------
__global__ void prep_wbf(const float* __restrict__ wgt, short* __restrict__ wbf)
{
    int idx = blockIdx.x * 256 + threadIdx.x;
    if (idx >= WBF_SHORTS) return;
    int o  = idx / WBF_COLS;
    int kp = idx % WBF_COLS;
    int cb = kp / 160, r = kp % 160;
    float v = 0.f;
    if (r < 144) {
        int tap = r >> 4;
        int c   = cb * 16 + (r & 15);
        v = wgt[(o * CIN + c) * KK + tap];
    }
    wbf[idx] = (short)f2bf(v);
}

// ---------------------------------------------------------------------------
// XCD band swizzle (kept from R3): xcd = bid % 8; T = (bid%8)*(n/8)+bid/8
// gives each XCD a contiguous band of tiles -> x-window rows reused ~12x
// inside the local 4 MB L2.
// ---------------------------------------------------------------------------

// ---------------------------------------------------------------------------
// offmask: 27-filter 3x3 conv. Block = 64 px (32 f x 8 pg of 8 px).
// ---------------------------------------------------------------------------
#define CC 8
__global__ __launch_bounds__(256) void offmask_kernel(
    const float* __restrict__ x, const float* __restrict__ wtap2,
    const float* __restrict__ bcat, float* __restrict__ offs,
    float* __restrict__ mask)
{
    const int bid = blockIdx.x;
    const int T = (bid & 7) * 128 + (bid >> 3);
    const int wo0 = (T & 1) * 64;
    const int ho  = (T >> 1) & 127;
    const int b   = T >> 8;
    const int tid = threadIdx.x;
    const int f   = tid & 31;
    const int pg  = tid >> 5;
    const int px0 = pg * 8;

    __shared__ float lx[CC * 3 * 72];     // 6,912 B (base x = wo0-1)
    __shared__ float lw2[CC * 32 * 12];   // 12,288 B

    float acc[8];
    #pragma unroll
    for (int i = 0; i < 8; ++i) acc[i] = 0.f;

    const float* xb = x + b * CIN * HW;

    for (int cb = 0; cb < CIN; cb += CC) {
        if (cb) __syncthreads();
        #pragma unroll
        for (int i = 0; i < 7; ++i) {
            int idx = tid + i * 256;
            if (idx < CC * 3 * 72) {
                int c  = idx / 216;
                int rem = idx % 216;
                int ry = rem / 72;
                int j  = rem % 72;
                int g  = wo0 - 1 + j;
                int y  = ho - 1 + ry;
                float v = (y >= 0 && y < H && g >= 0 && g < W)
                          ? xb[(cb + c) * HW + y * W + g] : 0.f;
                lx[idx] = v;
            }
        }
        #pragma unroll
        for (int i = 0; i < 12; ++i) {
            int idx = tid + i * 256;
            lw2[idx] = wtap2[cb * (32 * 12) + idx];
        }
        __syncthreads();
        #pragma unroll 1
        for (int c = 0; c < CC; ++c) {
            const float* wrow = &lw2[(c * 32 + f) * 12];
            f32x4 wq0 = *(const f32x4*)wrow;
            f32x4 wq1 = *(const f32x4*)(wrow + 4);
            float wv[9] = {wq0.x, wq0.y, wq0.z, wq0.w,
                           wq1.x, wq1.y, wq1.z, wq1.w, wrow[8]};
            float xr[3][10];
            #pragma unroll
            for (int q = 0; q < 3; ++q) {
                const float* xrow = &lx[(c * 3 + q) * 72 + px0];
                f32x4 xa = *(const f32x4*)xrow;
                f32x4 xb4 = *(const f32x4*)(xrow + 4);
                f32x2 xc = *(const f32x2*)(xrow + 8);
                xr[q][0] = xa.x;  xr[q][1] = xa.y;  xr[q][2] = xa.z;  xr[q][3] = xa.w;
                xr[q][4] = xb4.x; xr[q][5] = xb4.y; xr[q][6] = xb4.z; xr[q][7] = xb4.w;
                xr[q][8] = xc.x;  xr[q][9] = xc.y;
            }
            #pragma unroll
            for (int ky = 0; ky < 3; ++ky) {
                #pragma unroll
                for (int kx = 0; kx < 3; ++kx) {
                    float w = wv[ky * 3 + kx];
                    #pragma unroll
                    for (int p = 0; p < 8; ++p)
                        acc[p] += xr[ky][p + kx] * w;
                }
            }
        }
    }

    const float bv = bcat[f];
    if (f < 18) {
        float* op = offs + ((b * 18 + f) * H + ho) * W + wo0 + px0;
        #pragma unroll
        for (int p = 0; p < 8; ++p) op[p] = acc[p] + bv;
    } else if (f < 27) {
        float* mp = mask + ((b * 9 + (f - 18)) * H + ho) * W + wo0 + px0;
        #pragma unroll
        for (int p = 0; p < 8; ++p) {
            float a = acc[p] + bv;
            mp[p] = 1.f / (1.f + expf(-a));
        }
    }
}

// ---------------------------------------------------------------------------
// deform3: LDS-window sampling. Per 16-ch chunk: stage the 6-row x 72-col
// window (rows [ho-2,ho+3], cols [wo0-4,wo0+67], clamped rows / zeroed cols)
// with COALESCED loads from NCHW x, then sample bilinear corners from LDS
// (ds_read2_b32 pairs, stride-1 lane addressing -> ~2-way = free).
// Rare out-of-window slots take an exec-masked global fallback (exact math).
// MFMA of chunk cb-1 runs under the staging of chunk cb.
// LDS = 27,648 (XW) + 21,504 (S) = 48 KB -> 3 blocks/CU.
// ---------------------------------------------------------------------------
__global__ __launch_bounds__(256, 3) void deform3_kernel(
    const float* __restrict__ x, const float* __restrict__ offs,
    const float* __restrict__ maskp, const short* __restrict__ wbf,
    float* __restrict__ out)
{
    const int bid = blockIdx.x;
    const int T = (bid & 7) * 128 + (bid >> 3);
    const int wo0 = (T & 1) * 64;
    const int ho  = (T >> 1) & 127;
    const int b   = T >> 8;
    const int tid  = threadIdx.x;
    const int lane = tid & 63;
    const int wv   = tid >> 6;
    const int oh   = (wv & 1) * 64;
    const int ph   = (wv >> 1) * 32;
    const int row16 = lane & 15, kq = lane >> 4;

    __shared__ __align__(16) float XW[16 * 6 * 72];   // 27,648 B
    __shared__ __align__(16) short S[64 * LDK];       // 21,504 B

    if (tid < 128) {                      // zero K-pad [144,160) once
        short8 z = {0,0,0,0,0,0,0,0};
        *(short8*)&S[(tid >> 1) * LDK + 144 + (tid & 1) * 8] = z;
    }

    // ---- metadata: slot s = tid + j*256 -> (tap k = s>>6, px p = s&63) ----
    int   moff[3][2];                      // byte offsets (global fallback)
    int   lidx0[3], lidx1[3];              // LDS word offsets; lidx0<0 = slow
    float wA0[3], wB0[3], wA1[3], wB1[3];
    #pragma unroll
    for (int j = 0; j < 3; ++j) {
        moff[j][0] = 0; moff[j][1] = 0;
        lidx0[j] = -1; lidx1[j] = 0;
        wA0[j] = 0.f; wB0[j] = 0.f; wA1[j] = 0.f; wB1[j] = 0.f;
        int s = tid + j * 256;
        if (s < 576) {
            int k = s >> 6, p = s & 63;
            int wo = wo0 + p;
            int ky = k / 3, kx = k % 3;
            int obase = ((b * 18 + 2 * k) * H + ho) * W + wo;
            float dy = offs[obase];
            float dx = offs[obase + HW];
            float mk = maskp[((b * 9 + k) * H + ho) * W + wo];
            float py  = (float)(ho - 1 + ky) + dy;
            float pxf = (float)(wo - 1 + kx) + dx;
            float fy = floorf(py), fx = floorf(pxf);
            float ly = py - fy, lx = pxf - fx;
            int y0 = (int)fy, x0 = (int)fx;
            int y1 = y0 + 1,  x1 = x0 + 1;
            bool vy0 = (y0 >= 0) && (y0 < H);
            bool vy1 = (y1 >= 0) && (y1 < H);
            bool vx0 = (x0 >= 0) && (x0 < W);
            bool vx1 = (x1 >= 0) && (x1 < W);
            float w0 = (vy0 && vx0) ? (1.f - ly) * (1.f - lx) * mk : 0.f;
            float w1 = (vy0 && vx1) ? (1.f - ly) * lx * mk : 0.f;
            float w2 = (vy1 && vx0) ? ly * (1.f - lx) * mk : 0.f;
            float w3 = (vy1 && vx1) ? ly * lx * mk : 0.f;
            int lc = min(max(x0, 0), W - 2);
            bool sel = (x0 == lc);
            int r0 = min(max(y0, 0), H - 1);
            int r1 = min(max(y1, 0), H - 1);
            moff[j][0] = (r0 * W + lc) * 4;
            moff[j][1] = (r1 * W + lc) * 4;
            wA0[j] = sel ? w0 : w1;  wB0[j] = sel ? w1 : w0;
            wA1[j] = sel ? w2 : w3;  wB1[j] = sel ? w3 : w2;
            int u0 = r0 - (ho - 2);
            int u1 = r1 - (ho - 2);
            int vv = lc - (wo0 - 4);
            bool fastp = ((unsigned)u0 < 6u) && ((unsigned)u1 < 6u)
                       && ((unsigned)vv < 71u);
            lidx1[j] = u1 * 72 + vv;
            lidx0[j] = fastp ? (u0 * 72 + vv) : -1;
        }
    }

    f32x4 acc[4][2];
    #pragma unroll
    for (int i = 0; i < 4; ++i)
        #pragma unroll
        for (int j = 0; j < 2; ++j)
            acc[i][j] = (f32x4){0.f, 0.f, 0.f, 0.f};

    const float* xb = x + (size_t)b * CIN * HW;

    // ---- stage window for chunk cb: 1728 dwordx4, coalesced ----
    auto stage = [&](int cb) {
        #pragma unroll
        for (int t = 0; t < 7; ++t) {
            int idx = tid + t * 256;
            if (idx < 1728) {
                int ci  = idx / 108;
                int rem = idx % 108;
                int row = rem / 18;
                int q   = rem % 18;
                int ys  = min(max(ho - 2 + row, 0), H - 1);
                int g0  = wo0 - 4 + q * 4;
                const float* src = xb + (size_t)(cb * 16 + ci) * HW + ys * W;
                f32x4 v;
                if (g0 >= 0 && g0 <= W - 4) {
                    v = *(const f32x4*)(src + g0);
                } else {
                    v.x = ((unsigned)(g0 + 0) < (unsigned)W) ? src[g0 + 0] : 0.f;
                    v.y = ((unsigned)(g0 + 1) < (unsigned)W) ? src[g0 + 1] : 0.f;
                    v.z = ((unsigned)(g0 + 2) < (unsigned)W) ? src[g0 + 2] : 0.f;
                    v.w = ((unsigned)(g0 + 3) < (unsigned)W) ? src[g0 + 3] : 0.f;
                }
                *(f32x4*)&XW[(ci * 6 + row) * 72 + q * 4] = v;
            }
        }
    };

    // ---- sample chunk cb from XW (or global fallback), write S ----
    auto sample = [&](int cb) {
        #pragma unroll
        for (int j = 0; j < 3; ++j) {
            int s = tid + j * 256;
            if (s < 576) {
                int k = s >> 6, p = s & 63;
                float va[16];
                float wa0 = wA0[j], wb0 = wB0[j], wa1 = wA1[j], wb1 = wB1[j];
                if (lidx0[j] >= 0) {
                    int l0 = lidx0[j], l1 = lidx1[j];
                    #pragma unroll
                    for (int ci = 0; ci < 16; ++ci) {
                        const float* bp = &XW[ci * 432];
                        float a0 = bp[l0], a1 = bp[l0 + 1];
                        float b0 = bp[l1], b1 = bp[l1 + 1];
                        va[ci] = wa0 * a0 + wb0 * a1 + wa1 * b0 + wb1 * b1;
                    }
                } else {
                    #pragma unroll
                    for (int ci = 0; ci < 16; ++ci) {
                        const char* pc = (const char*)(xb + (size_t)(cb * 16 + ci) * HW);
                        f32x2 A  = *(const f32x2a*)(pc + moff[j][0]);
                        f32x2 Bv = *(const f32x2a*)(pc + moff[j][1]);
                        va[ci] = wa0 * A.x + wb0 * A.y + wa1 * Bv.x + wb1 * Bv.y;
                    }
                }
                short8 lo, hi;
                #pragma unroll
                for (int ci = 0; ci < 8; ++ci) lo[ci] = (short)f2bf(va[ci]);
                #pragma unroll
                for (int ci = 0; ci < 8; ++ci) hi[ci] = (short)f2bf(va[8 + ci]);
                *(short8*)&S[p * LDK + k * 16]     = lo;
                *(short8*)&S[p * LDK + k * 16 + 8] = hi;
            }
        }
    };

    // ---- one K=160 MFMA pass over S for chunk cb ----
    auto mfma_step = [&](int cb) {
        #pragma unroll
        for (int ks = 0; ks < 5; ++ks) {
            short8 a[4];
            #pragma unroll
            for (int of = 0; of < 4; ++of) {
                int o = oh + of * 16 + row16;
                a[of] = *(const short8*)(wbf + o * WBF_COLS + cb * 160 + ks * 32 + kq * 8);
            }
            #pragma unroll
            for (int pf = 0; pf < 2; ++pf) {
                int p = ph + pf * 16 + row16;
                short8 bfr = *(const short8*)&S[p * LDK + ks * 32 + kq * 8];
                #pragma unroll
                for (int of = 0; of < 4; ++of)
                    acc[of][pf] = __builtin_amdgcn_mfma_f32_16x16x32_bf16(
                        a[of], bfr, acc[of][pf], 0, 0, 0);
            }
        }
    };

    // ---- pipelined main loop: stage(cb) overlaps mfma(cb-1) ----
    stage(0);
    __syncthreads();
    sample(0);
    __syncthreads();
    #pragma unroll 1
    for (int cb = 1; cb < 4; ++cb) {
        stage(cb);          // writes XW (prev sample done at last barrier)
        mfma_step(cb - 1);  // reads S (written before last barrier)
        __syncthreads();
        sample(cb);         // reads XW(cb), overwrites S
        __syncthreads();
    }
    mfma_step(3);

    // ---- store: C/D layout col(px)=lane&15, row(o)=(lane>>4)*4+r ----
    #pragma unroll
    for (int of = 0; of < 4; ++of) {
        #pragma unroll
        for (int r = 0; r < 4; ++r) {
            int o = oh + of * 16 + kq * 4 + r;
            float* orow = out + ((b * COUT + o) * H + ho) * W;
            #pragma unroll
            for (int pf = 0; pf < 2; ++pf) {
                int wo = wo0 + ph + pf * 16 + row16;
                orow[wo] = acc[of][pf][r];
            }
        }
    }
}

// ---------------------------------------------------------------------------
extern "C" void kernel_launch(void* const* d_in, const int* in_sizes, int n_in,
                              void* d_out, int out_size, void* d_ws, size_t ws_size,
                              hipStream_t stream)
{
    const float* x      = (const float*)d_in[0];
    const float* w_off  = (const float*)d_in[1];
    const float* b_off  = (const float*)d_in[2];
    const float* w_mask = (const float*)d_in[3];
    const float* b_mask = (const float*)d_in[4];
    const float* weight = (const float*)d_in[5];
    float* out   = (float*)d_out;

    float* offs  = (float*)d_ws;
    float* maskb = offs + OFFS_SZ;
    float* bcat  = maskb + MASK_SZ;
    short* wbf   = (short*)(bcat + 32);
    float* wtap2 = bcat + 32 + WBF_SHORTS / 2;

    prep_kernel<<<dim3((WTAP2_SZ + 255) / 256), 256, 0, stream>>>(
        w_off, b_off, w_mask, b_mask, wtap2, bcat);
    prep_wbf<<<dim3((WBF_SHORTS + 255) / 256), 256, 0, stream>>>(weight, wbf);
    offmask_kernel<<<dim3(1024), 256, 0, stream>>>(x, wtap2, bcat, offs, maskb);
    deform3_kernel<<<dim3(1024), 256, 0, stream>>>(x, offs, maskb, wbf, out);
}

// Round 5
// 130.651 us; speedup vs baseline: 1.5944x; 1.0656x over previous
//
#include <hip/hip_runtime.h>
#include <math.h>

#define B 4
#define CIN 64
#define H 128
#define W 128
#define COUT 128
#define KK 9
#define HW (H*W)

#define OFFS_SZ (B*18*HW)
#define MASK_SZ (B*9*HW)
#define WTAP2_SZ (CIN*32*12)
#define WBF_COLS 640                 // 4 chunks x 160 (144 real + 16 zero)
#define WBF_SHORTS (COUT*WBF_COLS)
#define LDK 168                      // LDS k-stride (shorts); 336B row stride

typedef __attribute__((ext_vector_type(8))) short short8;
typedef __attribute__((ext_vector_type(4))) float f32x4;
typedef __attribute__((ext_vector_type(2))) float f32x2;
typedef f32x2 __attribute__((aligned(4))) f32x2a;   // align-4 float2 load

__device__ __forceinline__ unsigned short f2bf(float f) {
    unsigned int u = __float_as_uint(f);
    u += 0x7fffu + ((u >> 16) & 1u);
    return (unsigned short)(u >> 16);
}

// ---------------------------------------------------------------------------
// prep: wtap2[c][f][12] (offmask weights, t-contiguous for b128 LDS reads),
// bcat biases.
// ---------------------------------------------------------------------------
__global__ void prep_kernel(const float* __restrict__ w_off, const float* __restrict__ b_off,
                            const float* __restrict__ w_mask, const float* __restrict__ b_mask,
                            float* __restrict__ wtap2, float* __restrict__ bcat)
{
    int idx = blockIdx.x * 256 + threadIdx.x;
    if (idx < WTAP2_SZ) {
        int t = idx % 12;
        int f = (idx / 12) & 31;
        int c = idx / 384;
        float v = 0.f;
        if (t < 9) {
            if (f < 18)      v = w_off[(f * CIN + c) * 9 + t];
            else if (f < 27) v = w_mask[((f - 18) * CIN + c) * 9 + t];
        }
        wtap2[idx] = v;
    }
    if (blockIdx.x == 0 && threadIdx.x < 32) {
        int f = threadIdx.x;
        float bv = 0.f;
        if (f < 18) bv = b_off[f];
        else if (f < 27) bv = b_mask[f - 18];
        bcat[f] = bv;
    }
}

// ---------------------------------------------------------------------------
// prep_wbf: einsum weights -> bf16, layout [o][cb*160 + tap*16 + ci];
// pad cols [144,160) per chunk are ZERO.
// ---------------------------------------------------------------------------
__global__ void prep_wbf(const float* __restrict__ wgt, short* __restrict__ wbf)
{
    int idx = blockIdx.x * 256 + threadIdx.x;
    if (idx >= WBF_SHORTS) return;
    int o  = idx / WBF_COLS;
    int kp = idx % WBF_COLS;
    int cb = kp / 160, r = kp % 160;
    float v = 0.f;
    if (r < 144) {
        int tap = r >> 4;
        int c   = cb * 16 + (r & 15);
        v = wgt[(o * CIN + c) * KK + tap];
    }
    wbf[idx] = (short)f2bf(v);
}

// ---------------------------------------------------------------------------
// XCD band swizzle (kept): T = (bid%8)*(n/8)+bid/8 gives each XCD a
// contiguous band of tiles -> window rows reused inside the local 4 MB L2.
// ---------------------------------------------------------------------------

// ---------------------------------------------------------------------------
// offmask: 27-filter 3x3 conv. Block = 64 px (32 f x 8 pg of 8 px).
// This round: async-split staging (issue next chunk's global loads into
// registers BEFORE compute, ds_write after) + channel loop unroll 2 so
// LDS-read latency of c+1 hides under c's FMAs.
// ---------------------------------------------------------------------------
#define CC 8
__global__ __launch_bounds__(256, 4) void offmask_kernel(
    const float* __restrict__ x, const float* __restrict__ wtap2,
    const float* __restrict__ bcat, float* __restrict__ offs,
    float* __restrict__ mask)
{
    const int bid = blockIdx.x;
    const int T = (bid & 7) * 128 + (bid >> 3);
    const int wo0 = (T & 1) * 64;
    const int ho  = (T >> 1) & 127;
    const int b   = T >> 8;
    const int tid = threadIdx.x;
    const int f   = tid & 31;
    const int pg  = tid >> 5;
    const int px0 = pg * 8;

    __shared__ float lx[CC * 3 * 72];     // 6,912 B (base x = wo0-1)
    __shared__ float lw2[CC * 32 * 12];   // 12,288 B

    float acc[8];
    #pragma unroll
    for (int i = 0; i < 8; ++i) acc[i] = 0.f;

    const float* xb = x + b * CIN * HW;

    // register-staged loads for one chunk (7 x-slots + 12 w-slots)
    float nx[7], nw[12];
    auto load_chunk = [&](int cb) {
        #pragma unroll
        for (int i = 0; i < 7; ++i) {
            int idx = tid + i * 256;
            float v = 0.f;
            if (idx < CC * 3 * 72) {
                int c  = idx / 216;
                int rem = idx % 216;
                int ry = rem / 72;
                int j  = rem % 72;
                int g  = wo0 - 1 + j;
                int y  = ho - 1 + ry;
                if (y >= 0 && y < H && g >= 0 && g < W)
                    v = xb[(cb + c) * HW + y * W + g];
            }
            nx[i] = v;
        }
        #pragma unroll
        for (int i = 0; i < 12; ++i)
            nw[i] = wtap2[cb * (32 * 12) + tid + i * 256];
    };
    auto store_chunk = [&]() {
        #pragma unroll
        for (int i = 0; i < 7; ++i) {
            int idx = tid + i * 256;
            if (idx < CC * 3 * 72) lx[idx] = nx[i];
        }
        #pragma unroll
        for (int i = 0; i < 12; ++i)
            lw2[tid + i * 256] = nw[i];
    };

    load_chunk(0);
    store_chunk();
    __syncthreads();

    for (int cb = 0; cb < CIN; cb += CC) {
        bool more = (cb + CC) < CIN;
        if (more) load_chunk(cb + CC);   // in-flight during compute below

        #pragma unroll 2
        for (int c = 0; c < CC; ++c) {
            const float* wrow = &lw2[(c * 32 + f) * 12];
            f32x4 wq0 = *(const f32x4*)wrow;
            f32x4 wq1 = *(const f32x4*)(wrow + 4);
            float wv[9] = {wq0.x, wq0.y, wq0.z, wq0.w,
                           wq1.x, wq1.y, wq1.z, wq1.w, wrow[8]};
            float xr[3][10];
            #pragma unroll
            for (int q = 0; q < 3; ++q) {
                const float* xrow = &lx[(c * 3 + q) * 72 + px0];
                f32x4 xa = *(const f32x4*)xrow;
                f32x4 xb4 = *(const f32x4*)(xrow + 4);
                f32x2 xc = *(const f32x2*)(xrow + 8);
                xr[q][0] = xa.x;  xr[q][1] = xa.y;  xr[q][2] = xa.z;  xr[q][3] = xa.w;
                xr[q][4] = xb4.x; xr[q][5] = xb4.y; xr[q][6] = xb4.z; xr[q][7] = xb4.w;
                xr[q][8] = xc.x;  xr[q][9] = xc.y;
            }
            #pragma unroll
            for (int ky = 0; ky < 3; ++ky) {
                #pragma unroll
                for (int kx = 0; kx < 3; ++kx) {
                    float w = wv[ky * 3 + kx];
                    #pragma unroll
                    for (int p = 0; p < 8; ++p)
                        acc[p] += xr[ky][p + kx] * w;
                }
            }
        }

        if (more) {
            __syncthreads();     // all reads of lx/lw2 done
            store_chunk();
            __syncthreads();
        }
    }

    const float bv = bcat[f];
    if (f < 18) {
        float* op = offs + ((b * 18 + f) * H + ho) * W + wo0 + px0;
        #pragma unroll
        for (int p = 0; p < 8; ++p) op[p] = acc[p] + bv;
    } else if (f < 27) {
        float* mp = mask + ((b * 9 + (f - 18)) * H + ho) * W + wo0 + px0;
        #pragma unroll
        for (int p = 0; p < 8; ++p) {
            float a = acc[p] + bv;
            mp[p] = 1.f / (1.f + expf(-a));
        }
    }
}

// ---------------------------------------------------------------------------
// deform4: LDS-window sampling, 8-channel half-chunks.
// XW holds 8 ch x 6 rows x 72 cols f32 (13,824 B); S holds one 16-ch chunk's
// K=160 bf16 (21,504 B). Total 35,328 B -> 4 blocks/CU (no straggler round).
// Per half h: stage 8-ch window (coalesced), sample -> ci-half of S;
// MFMA K=160 of chunk c overlaps stage of half 2c+2.
// ---------------------------------------------------------------------------
__global__ __launch_bounds__(256, 4) void deform4_kernel(
    const float* __restrict__ x, const float* __restrict__ offs,
    const float* __restrict__ maskp, const short* __restrict__ wbf,
    float* __restrict__ out)
{
    const int bid = blockIdx.x;
    const int T = (bid & 7) * 128 + (bid >> 3);
    const int wo0 = (T & 1) * 64;
    const int ho  = (T >> 1) & 127;
    const int b   = T >> 8;
    const int tid  = threadIdx.x;
    const int lane = tid & 63;
    const int wv   = tid >> 6;
    const int oh   = (wv & 1) * 64;
    const int ph   = (wv >> 1) * 32;
    const int row16 = lane & 15, kq = lane >> 4;

    __shared__ __align__(16) float XW[8 * 6 * 72];    // 13,824 B
    __shared__ __align__(16) short S[64 * LDK];       // 21,504 B

    if (tid < 128) {                      // zero K-pad [144,160) once
        short8 z = {0,0,0,0,0,0,0,0};
        *(short8*)&S[(tid >> 1) * LDK + 144 + (tid & 1) * 8] = z;
    }

    // ---- metadata: slot s = tid + j*256 -> (tap k = s>>6, px p = s&63) ----
    int   moff[3][2];                      // byte offsets (global fallback)
    int   lidx0[3], lidx1[3];              // LDS word offsets; lidx0<0 = slow
    float wA0[3], wB0[3], wA1[3], wB1[3];
    #pragma unroll
    for (int j = 0; j < 3; ++j) {
        moff[j][0] = 0; moff[j][1] = 0;
        lidx0[j] = -1; lidx1[j] = 0;
        wA0[j] = 0.f; wB0[j] = 0.f; wA1[j] = 0.f; wB1[j] = 0.f;
        int s = tid + j * 256;
        if (s < 576) {
            int k = s >> 6, p = s & 63;
            int wo = wo0 + p;
            int ky = k / 3, kx = k % 3;
            int obase = ((b * 18 + 2 * k) * H + ho) * W + wo;
            float dy = offs[obase];
            float dx = offs[obase + HW];
            float mk = maskp[((b * 9 + k) * H + ho) * W + wo];
            float py  = (float)(ho - 1 + ky) + dy;
            float pxf = (float)(wo - 1 + kx) + dx;
            float fy = floorf(py), fx = floorf(pxf);
            float ly = py - fy, lx = pxf - fx;
            int y0 = (int)fy, x0 = (int)fx;
            int y1 = y0 + 1,  x1 = x0 + 1;
            bool vy0 = (y0 >= 0) && (y0 < H);
            bool vy1 = (y1 >= 0) && (y1 < H);
            bool vx0 = (x0 >= 0) && (x0 < W);
            bool vx1 = (x1 >= 0) && (x1 < W);
            float w0 = (vy0 && vx0) ? (1.f - ly) * (1.f - lx) * mk : 0.f;
            float w1 = (vy0 && vx1) ? (1.f - ly) * lx * mk : 0.f;
            float w2 = (vy1 && vx0) ? ly * (1.f - lx) * mk : 0.f;
            float w3 = (vy1 && vx1) ? ly * lx * mk : 0.f;
            int lc = min(max(x0, 0), W - 2);
            bool sel = (x0 == lc);
            int r0 = min(max(y0, 0), H - 1);
            int r1 = min(max(y1, 0), H - 1);
            moff[j][0] = (r0 * W + lc) * 4;
            moff[j][1] = (r1 * W + lc) * 4;
            wA0[j] = sel ? w0 : w1;  wB0[j] = sel ? w1 : w0;
            wA1[j] = sel ? w2 : w3;  wB1[j] = sel ? w3 : w2;
            int u0 = r0 - (ho - 2);
            int u1 = r1 - (ho - 2);
            int vvv = lc - (wo0 - 4);
            bool fastp = ((unsigned)u0 < 6u) && ((unsigned)u1 < 6u)
                       && ((unsigned)vvv < 71u);
            lidx1[j] = u1 * 72 + vvv;
            lidx0[j] = fastp ? (u0 * 72 + vvv) : -1;
        }
    }

    f32x4 acc[4][2];
    #pragma unroll
    for (int i = 0; i < 4; ++i)
        #pragma unroll
        for (int j = 0; j < 2; ++j)
            acc[i][j] = (f32x4){0.f, 0.f, 0.f, 0.f};

    const float* xb = x + (size_t)b * CIN * HW;

    // ---- stage 8-ch window for half h: 864 dwordx4, coalesced ----
    auto stage = [&](int h) {
        #pragma unroll
        for (int t = 0; t < 4; ++t) {
            int idx = tid + t * 256;
            if (idx < 864) {
                int ci  = idx / 108;
                int rem = idx % 108;
                int row = rem / 18;
                int q   = rem % 18;
                int ys  = min(max(ho - 2 + row, 0), H - 1);
                int g0  = wo0 - 4 + q * 4;
                const float* src = xb + (size_t)(h * 8 + ci) * HW + ys * W;
                f32x4 v;
                if (g0 >= 0 && g0 <= W - 4) {
                    v = *(const f32x4*)(src + g0);
                } else {
                    v.x = ((unsigned)(g0 + 0) < (unsigned)W) ? src[g0 + 0] : 0.f;
                    v.y = ((unsigned)(g0 + 1) < (unsigned)W) ? src[g0 + 1] : 0.f;
                    v.z = ((unsigned)(g0 + 2) < (unsigned)W) ? src[g0 + 2] : 0.f;
                    v.w = ((unsigned)(g0 + 3) < (unsigned)W) ? src[g0 + 3] : 0.f;
                }
                *(f32x4*)&XW[(ci * 6 + row) * 72 + q * 4] = v;
            }
        }
    };

    // ---- sample half h from XW (or global fallback), write ci-half of S ----
    auto sample = [&](int h) {
        #pragma unroll
        for (int j = 0; j < 3; ++j) {
            int s = tid + j * 256;
            if (s < 576) {
                int k = s >> 6, p = s & 63;
                float va[8];
                float wa0 = wA0[j], wb0 = wB0[j], wa1 = wA1[j], wb1 = wB1[j];
                if (lidx0[j] >= 0) {
                    int l0 = lidx0[j], l1 = lidx1[j];
                    #pragma unroll
                    for (int ci = 0; ci < 8; ++ci) {
                        const float* bp = &XW[ci * 432];
                        float a0 = bp[l0], a1 = bp[l0 + 1];
                        float b0 = bp[l1], b1 = bp[l1 + 1];
                        va[ci] = wa0 * a0 + wb0 * a1 + wa1 * b0 + wb1 * b1;
                    }
                } else {
                    #pragma unroll
                    for (int ci = 0; ci < 8; ++ci) {
                        const char* pc = (const char*)(xb + (size_t)(h * 8 + ci) * HW);
                        f32x2 A  = *(const f32x2a*)(pc + moff[j][0]);
                        f32x2 Bv = *(const f32x2a*)(pc + moff[j][1]);
                        va[ci] = wa0 * A.x + wb0 * A.y + wa1 * Bv.x + wb1 * Bv.y;
                    }
                }
                short8 sv;
                #pragma unroll
                for (int ci = 0; ci < 8; ++ci) sv[ci] = (short)f2bf(va[ci]);
                *(short8*)&S[p * LDK + k * 16 + (h & 1) * 8] = sv;
            }
        }
    };

    // ---- one K=160 MFMA pass over S for chunk c ----
    auto mfma_step = [&](int c) {
        #pragma unroll
        for (int ks = 0; ks < 5; ++ks) {
            short8 a[4];
            #pragma unroll
            for (int of = 0; of < 4; ++of) {
                int o = oh + of * 16 + row16;
                a[of] = *(const short8*)(wbf + o * WBF_COLS + c * 160 + ks * 32 + kq * 8);
            }
            #pragma unroll
            for (int pf = 0; pf < 2; ++pf) {
                int p = ph + pf * 16 + row16;
                short8 bfr = *(const short8*)&S[p * LDK + ks * 32 + kq * 8];
                #pragma unroll
                for (int of = 0; of < 4; ++of)
                    acc[of][pf] = __builtin_amdgcn_mfma_f32_16x16x32_bf16(
                        a[of], bfr, acc[of][pf], 0, 0, 0);
            }
        }
    };

    // ---- pipeline: halves 0..7; mfma(c) overlaps stage(2c+2) ----
    stage(0); __syncthreads(); sample(0); __syncthreads();
    stage(1); __syncthreads(); sample(1); __syncthreads();
    #pragma unroll 1
    for (int c = 0; c < 3; ++c) {
        stage(2 * c + 2);
        mfma_step(c);          // reads S (complete), XW untouched by mfma
        __syncthreads();
        sample(2 * c + 2);     // overwrites ci-half 0 of S
        __syncthreads();
        stage(2 * c + 3);
        __syncthreads();
        sample(2 * c + 3);
        __syncthreads();
    }
    mfma_step(3);

    // ---- store: C/D layout col(px)=lane&15, row(o)=(lane>>4)*4+r ----
    #pragma unroll
    for (int of = 0; of < 4; ++of) {
        #pragma unroll
        for (int r = 0; r < 4; ++r) {
            int o = oh + of * 16 + kq * 4 + r;
            float* orow = out + ((b * COUT + o) * H + ho) * W;
            #pragma unroll
            for (int pf = 0; pf < 2; ++pf) {
                int wo = wo0 + ph + pf * 16 + row16;
                orow[wo] = acc[of][pf][r];
            }
        }
    }
}

// ---------------------------------------------------------------------------
extern "C" void kernel_launch(void* const* d_in, const int* in_sizes, int n_in,
                              void* d_out, int out_size, void* d_ws, size_t ws_size,
                              hipStream_t stream)
{
    const float* x      = (const float*)d_in[0];
    const float* w_off  = (const float*)d_in[1];
    const float* b_off  = (const float*)d_in[2];
    const float* w_mask = (const float*)d_in[3];
    const float* b_mask = (const float*)d_in[4];
    const float* weight = (const float*)d_in[5];
    float* out   = (float*)d_out;

    float* offs  = (float*)d_ws;
    float* maskb = offs + OFFS_SZ;
    float* bcat  = maskb + MASK_SZ;
    short* wbf   = (short*)(bcat + 32);
    float* wtap2 = bcat + 32 + WBF_SHORTS / 2;

    prep_kernel<<<dim3((WTAP2_SZ + 255) / 256), 256, 0, stream>>>(
        w_off, b_off, w_mask, b_mask, wtap2, bcat);
    prep_wbf<<<dim3((WBF_SHORTS + 255) / 256), 256, 0, stream>>>(weight, wbf);
    offmask_kernel<<<dim3(1024), 256, 0, stream>>>(x, wtap2, bcat, offs, maskb);
    deform4_kernel<<<dim3(1024), 256, 0, stream>>>(x, offs, maskb, wbf, out);
}